// Round 11
// baseline (118.286 us; speedup 1.0000x reference)
//
#include <hip/hip_runtime.h>
#include <hip/hip_bf16.h>
#include <math.h>

#define C0 8
#define C1 4
#define NCH 20          // C0 + 3*C1
#define NQ 16
#define K3 125
#define G 8
#define RMAX 5.5f
#define EPSL 1e-6f

#define KD1 2048        // gemm1 K = 128 taps * 16 q
#define PHI_N 1048576   // 512 * 2048
#define VOX_N 34560     // 20*12*12*12 voxels (xtp, 16 q each)
#define W2_N 20480      // 32*20*32
#define E2C_B 10485760  // bytes per kc chunk of E2: 16*20*512*32*2

#define LDS_A 8192      // one A buffer: 64 rows * 128 B (XOR-swizzled, DMA-written)
#define LDS_B 18432     // 4 az-planes x 12x12x16 bf16 (per-kc slab) at offset 2*LDS_A
#define LDS_SZ 34816    // 2*8192 + 18432 (>= epilogue 2*8704) -> 4 blocks/CU

using f32x4 = __attribute__((ext_vector_type(4))) float;
using s16x8 = __attribute__((ext_vector_type(8))) short;

typedef const __attribute__((address_space(1))) unsigned int gq_t;
typedef __attribute__((address_space(3))) unsigned int lq_t;

__device__ __forceinline__ float epsf(int i, int m, int j) {
    if (i == m || m == j || i == j) return 0.f;
    return (m == (i + 1) % 3) ? 1.f : -1.f;
}

__device__ __forceinline__ unsigned short bf16bits(float v) {
    union { __hip_bfloat16 b; unsigned short u; } cv;
    cv.b = __float2bfloat16(v);
    return cv.u;
}

// ---------------- prep: phi, xtp, w2 (bf16) ----------------
// phi[m=p*32+b][t*16+q]  b = g*4+mi, mi: 0=R, 1..3 = R*u_{z,y,x}; t>=125 zero
// xtp[c][az][ay][ax][q]  zero-padded 12^3 (one thread per voxel, 16-q loop: coalesced)
// w2 [o=32pad][c=20][b=32]
__global__ __launch_bounds__(256) void prep_kernel(
    const float* __restrict__ x,
    const float* __restrict__ q_in, const float* __restrict__ q_out,
    const float* __restrict__ w_ss, const float* __restrict__ w_vs,
    const float* __restrict__ w_sv, const float* __restrict__ w_vv0,
    const float* __restrict__ w_vv1,
    __hip_bfloat16* __restrict__ phi, __hip_bfloat16* __restrict__ xtp,
    __hip_bfloat16* __restrict__ w2)
{
    int gid = blockIdx.x * 256 + threadIdx.x;   // exact grid
    if (gid < PHI_N) {
        int col = gid & (KD1 - 1); int m = gid >> 11;
        int t = col >> 4, q = col & 15;
        int p = m >> 5,  b = m & 31;
        int g = b >> 2,  mi = b & 3;
        float val = 0.f;
        if (t < K3) {
            int tz = t / 25, ty = (t / 5) % 5, tx = t % 5;
            float vz = (float)(tz - 2) - (q_out[p*3+0] - q_in[q*3+0]);
            float vy = (float)(ty - 2) - (q_out[p*3+1] - q_in[q*3+1]);
            float vx = (float)(tx - 2) - (q_out[p*3+2] - q_in[q*3+2]);
            float r  = sqrtf(vz*vz + vy*vy + vx*vx);
            float inv = (r > EPSL) ? (1.0f / r) : 0.0f;
            const float sigma = RMAX / (float)(G - 1);
            float d = (r - (RMAX * (float)g / (float)(G - 1))) / sigma;
            float Rg = expf(-0.5f * d * d);
            float u = (mi == 1) ? vz*inv : ((mi == 2) ? vy*inv : vx*inv);
            val = (mi == 0) ? Rg : Rg * u;
        }
        phi[gid] = __float2bfloat16(val);
    } else if (gid < PHI_N + VOX_N) {
        int vox = gid - PHI_N;
        int c   = vox / 1728;
        int rem = vox - c * 1728;
        int az = rem / 144;
        int ay = (rem / 12) % 12;
        int ax = rem % 12;
        int iz = az - 2, iy = ay - 2, ix = ax - 2;
        bool valid = ((unsigned)iz < 8u) & ((unsigned)iy < 8u) & ((unsigned)ix < 8u);
        int xoff = (iz << 6) + (iy << 3) + ix;
        union { s16x8 v[2]; unsigned short h[16]; } pk;
        #pragma unroll
        for (int q = 0; q < 16; ++q) {
            float v = valid ? x[((c * NQ + q) << 9) + xoff] : 0.f;
            pk.h[q] = bf16bits(v);
        }
        s16x8* dst = (s16x8*)(xtp + vox * 16);
        dst[0] = pk.v[0];
        dst[1] = pk.v[1];
    } else {
        int id = gid - (PHI_N + VOX_N);
        int b = id & 31; int r = id >> 5;
        int c = r % NCH; int o = r / NCH;
        int g = b >> 2,  mi = b & 3;
        float val = 0.f;
        if (o < NCH) {
            if (o < C0) {
                if (c < C0) { if (mi == 0) val = w_ss[(o * C0 + c) * G + g]; }
                else { int cv = (c - C0) / 3, j = (c - C0) % 3;
                       if (mi == 1 + j) val = w_sv[(o * C1 + cv) * G + g]; }
            } else {
                int ov = (o - C0) / 3, i = (o - C0) % 3;
                if (c < C0) { if (mi == 1 + i) val = w_vs[(ov * C0 + c) * G + g]; }
                else {
                    int cv = (c - C0) / 3, j = (c - C0) % 3;
                    if (mi == 0) { if (i == j) val = w_vv0[(ov * C1 + cv) * G + g]; }
                    else val = 0.7071067811865476f * w_vv1[(ov * C1 + cv) * G + g]
                               * epsf(i, mi - 1, j);
                }
            }
        }
        w2[id] = __float2bfloat16(val);
    }
}

// ---------------- gemm1: 2-wave blocks (64m x 128z), 1280 = 5/CU exactly, dbuf A-DMA ----------------
// grid 1280 = kc(2) x mg(8: 64 m-rows = 2 p's) x c(20) x zq(4: 128 z)
// block 128 thr = 2 waves (z-halves); 16 chunks of 64 k-elems (4 taps)
// Per j: [lgkm0;bar] -> issue DMA(j+1) -> [vmcnt(4);bar] -> compute(j).
// 4 blocks/CU resident, perfectly balanced grid; barriers sync only 2 waves.
__global__ __launch_bounds__(128, 2) void gemm1_kernel(
    const char* __restrict__ phi_b, const char* __restrict__ xtp_b,
    char* __restrict__ E2_b)
{
    __shared__ __align__(16) char lds[LDS_SZ];

    int tid = threadIdx.x;
    int wave = tid >> 6, lane = tid & 63;   // wave = z-half (old wj)
    int row = lane & 15, quad = lane >> 4;
    int hi = quad >> 1;

    int bi = blockIdx.x;                 // 1280
    int kc = bi / 640;
    int r  = bi - kc * 640;
    int mg = r / 80;                     // 8: which 64-row m-slice
    int r2 = r - mg * 80;
    int c  = r2 >> 2;
    int zq = r2 & 3;

    // ---- A DMA source pointers: wave w writes chunks w*4+i (i<4), 1KB each; 8KB = 64 rows.
    // lane dest d = chunk*1024 + lane*16; source elem = d ^ ((d>>7&7)<<4) (involution)
    // -> row = mg*64 + wave*32 + i*8 + (lane>>3), col-slot = (lane&7)^((lane>>3)&7).
    const char* gA[4];
    {
        int lrow = lane >> 3;
        int cslot = (lane & 7) ^ (lrow & 7);
        #pragma unroll
        for (int i = 0; i < 4; ++i)
            gA[i] = phi_b + (size_t)(mg * 64 + wave * 32 + i * 8 + lrow) * 4096
                    + kc * 2048 + cslot * 16;
    }
    int arx = (row & 7) << 4;            // af read-side XOR key

    // ---- B slab via DMA: xtp[c][az = 2zq+2kc .. +3][ay][ax][q], 18432 B = 18 issues (9/wave).
    // dest chunk y = k*64 + lane (linear). Read does LDS[g(L)] -> source uses g^{-1}
    // (back-substitution on chunk bits 0-2; bits >=3 and k*64 untouched).
    {
        int b0 = lane & 1, b1 = (lane >> 1) & 1, b2 = (lane >> 2) & 1, b3 = (lane >> 3) & 1;
        int i2 = b2 ^ b3;
        int i1 = b1 ^ i2;
        int i0 = b0 ^ i1;
        int slane = (lane & 56) | (i2 << 2) | (i1 << 1) | i0;
        const char* bsrc = xtp_b + c * 55296 + (zq + kc) * 9216 + slane * 16;
        for (int k = wave; k < 18; k += 2)
            __builtin_amdgcn_global_load_lds(
                (gq_t*)(bsrc + k * 1024),
                (lq_t*)(lds + 2 * LDS_A + k * 1024), 16, 0, 0);
    }

    // per-lane B LDS pre-offsets (linear; forward swizzle applied at read)
    int bpre[4];
    #pragma unroll
    for (int nt = 0; nt < 4; ++nt) {
        int zl = wave * 64 + nt * 16 + row;
        int zz = zl >> 6, zy = (zl >> 3) & 7, zx = zl & 7;
        bpre[nt] = (zz * 144 + zy * 12 + zx) * 32 + (quad & 1) * 16;
    }

    f32x4 acc[4][4];
    #pragma unroll
    for (int i = 0; i < 4; ++i)
        #pragma unroll
        for (int j = 0; j < 4; ++j) acc[i][j] = (f32x4){0.f, 0.f, 0.f, 0.f};

    // ---- prologue: DMA A(0) into buf0; drain everything; barrier (B + A0 visible) ----
    #pragma unroll
    for (int i = 0; i < 4; ++i)
        __builtin_amdgcn_global_load_lds(
            (gq_t*)(gA[i]), (lq_t*)(lds + (wave * 4 + i) * 1024), 16, 0, 0);
    asm volatile("s_waitcnt vmcnt(0) lgkmcnt(0)" ::: "memory");
    __builtin_amdgcn_sched_barrier(0);
    __builtin_amdgcn_s_barrier();
    __builtin_amdgcn_sched_barrier(0);

    int cur = 0;
    for (int j = 0; j < 16; ++j) {
        // (A) overwrite-safety: both waves' LDS reads of buf[cur^1] (compute j-1) retired
        asm volatile("s_waitcnt lgkmcnt(0)" ::: "memory");
        __builtin_amdgcn_sched_barrier(0);
        __builtin_amdgcn_s_barrier();
        __builtin_amdgcn_sched_barrier(0);
        if (j < 15) {
            #pragma unroll
            for (int i = 0; i < 4; ++i)
                __builtin_amdgcn_global_load_lds(
                    (gq_t*)(gA[i] + (j + 1) * 128),
                    (lq_t*)(lds + (cur ^ 1) * LDS_A + (wave * 4 + i) * 1024), 16, 0, 0);
            asm volatile("s_waitcnt vmcnt(4)" ::: "memory");   // DMA(j) done; DMA(j+1) in flight
        } else {
            asm volatile("s_waitcnt vmcnt(0)" ::: "memory");   // drain last chunk
        }
        __builtin_amdgcn_sched_barrier(0);
        __builtin_amdgcn_s_barrier();      // (B) A(j) visible from both waves
        __builtin_amdgcn_sched_barrier(0);

        int toff[4];
        #pragma unroll
        for (int tt = 0; tt < 4; ++tt) {
            int t = kc * 64 + j * 4 + tt; if (t > 124) t = 124;  // pad taps: phi=0
            int tz = t / 25, trm = t - tz * 25;
            int ty = trm / 5, tx = trm - ty * 5;
            toff[tt] = ((tz - 2 * kc) * 144 + ty * 12 + tx) * 32;  // per-kc plane base
        }
        #pragma unroll
        for (int st = 0; st < 2; ++st) {
            s16x8 af[4], bf[4];
            #pragma unroll
            for (int mt = 0; mt < 4; ++mt) {
                int aa = ((mt * 16 + row) * 128 + (st * 4 + quad) * 16) ^ arx;
                af[mt] = *(const s16x8*)(lds + cur * LDS_A + aa);
            }
            int tsel = toff[st * 2 + hi];
            #pragma unroll
            for (int nt = 0; nt < 4; ++nt) {
                int ba = bpre[nt] + tsel;
                ba ^= ((ba >> 5) & 7) << 4;
                bf[nt] = *(const s16x8*)(lds + 2 * LDS_A + ba);
            }
            #pragma unroll
            for (int mt = 0; mt < 4; ++mt)
                #pragma unroll
                for (int nt = 0; nt < 4; ++nt)
                    acc[mt][nt] = __builtin_amdgcn_mfma_f32_16x16x32_bf16(
                        af[mt], bf[nt], acc[mt][nt], 0, 0, 0);
        }
        cur ^= 1;
    }
    __syncthreads();                     // all compute done; LDS reusable

    // ---- epilogue: wave-private LDS transpose -> 1KB-contiguous stores ----
    int wbase = wave * 8704;                     // 64 zl x 136 B
    #pragma unroll
    for (int mt = 0; mt < 4; ++mt) {
        #pragma unroll
        for (int nt = 0; nt < 4; ++nt) {
            int zl = nt * 16 + row;
            union { unsigned long long u; __hip_bfloat16 h[4]; } pk;
            pk.h[0] = __float2bfloat16(acc[mt][nt][0]);
            pk.h[1] = __float2bfloat16(acc[mt][nt][1]);
            pk.h[2] = __float2bfloat16(acc[mt][nt][2]);
            pk.h[3] = __float2bfloat16(acc[mt][nt][3]);
            *(unsigned long long*)(lds + wbase + zl * 136 + (mt * 16 + quad * 4) * 2) = pk.u;
        }
    }
    // wave-local exchange: no barrier needed
    char* Ek = E2_b + (size_t)kc * E2C_B;
    int pbase = mg * 2;
    #pragma unroll
    for (int it = 0; it < 8; ++it) {
        int item = lane + it * 64;
        int piece = item & 3;
        int zl = (item >> 2) & 63;
        int h  = item >> 8;
        s16x8 v = *(const s16x8*)(lds + wbase + zl * 136 + h * 64 + piece * 16);
        int p = pbase + h;
        int z = zq * 128 + wave * 64 + zl;
        *(s16x8*)(Ek + ((size_t)((p * NCH + c) << 9) + z) * 64 + piece * 16) = v;
    }
}

// ---------------- gemm2: 4-way K-split + LDS reduce, direct store (no atomics) ----------------
// grid 256 = p(16) x zb(16: 32 z); block 512 thr = 8 waves = zh(2: 16-z half) x ks(4: K=320)
__global__ __launch_bounds__(512) void gemm2_kernel(
    const char* __restrict__ w2_b, const char* __restrict__ E2_b,
    const float* __restrict__ bias, float* __restrict__ out)
{
    __shared__ float red[3][2][64][8];   // [ks-1][zh][lane][mt*4+ri]

    int tid = threadIdx.x;
    int wave = tid >> 6, lane = tid & 63;
    int row = lane & 15, quad = lane >> 4;
    int zh = wave & 1, ks = wave >> 1;
    int bi = blockIdx.x;                 // 256
    int p  = bi >> 4;
    int zb = bi & 15;
    int z  = zb * 32 + zh * 16 + row;

    int kcq = ks >> 1;                   // kc chunk
    int cb  = (ks & 1) * 10;             // cc base within chunk
    const char* bbase = E2_b + (size_t)kcq * E2C_B + (size_t)p * 655360
                        + (size_t)z * 64 + quad * 16;

    f32x4 acc[2];
    acc[0] = (f32x4){0.f, 0.f, 0.f, 0.f};
    acc[1] = (f32x4){0.f, 0.f, 0.f, 0.f};

    #pragma unroll
    for (int ci = 0; ci < 10; ++ci) {
        int cc = cb + ci;
        s16x8 a0 = *(const s16x8*)(w2_b + (row)      * 1280 + cc * 64 + quad * 16);
        s16x8 a1 = *(const s16x8*)(w2_b + (16 + row) * 1280 + cc * 64 + quad * 16);
        s16x8 b  = *(const s16x8*)(bbase + (size_t)cc * 32768);
        acc[0] = __builtin_amdgcn_mfma_f32_16x16x32_bf16(a0, b, acc[0], 0, 0, 0);
        acc[1] = __builtin_amdgcn_mfma_f32_16x16x32_bf16(a1, b, acc[1], 0, 0, 0);
    }

    if (ks != 0) {
        #pragma unroll
        for (int mt = 0; mt < 2; ++mt)
            #pragma unroll
            for (int ri = 0; ri < 4; ++ri)
                red[ks - 1][zh][lane][mt * 4 + ri] = acc[mt][ri];
    }
    __syncthreads();
    if (ks == 0) {
        #pragma unroll
        for (int s = 0; s < 3; ++s)
            #pragma unroll
            for (int mt = 0; mt < 2; ++mt)
                #pragma unroll
                for (int ri = 0; ri < 4; ++ri)
                    acc[mt][ri] += red[s][zh][lane][mt * 4 + ri];
        #pragma unroll
        for (int mt = 0; mt < 2; ++mt)
            #pragma unroll
            for (int ri = 0; ri < 4; ++ri) {
                int o = mt * 16 + quad * 4 + ri;
                if (o < NCH) {
                    float v = acc[mt][ri];
                    if (o < C0) v += bias[o];
                    out[((o * NQ + p) << 9) + z] = v;
                }
            }
    }
}

extern "C" void kernel_launch(void* const* d_in, const int* in_sizes, int n_in,
                              void* d_out, int out_size, void* d_ws, size_t ws_size,
                              hipStream_t stream) {
    const float* x     = (const float*)d_in[0];
    const float* q_in  = (const float*)d_in[1];
    const float* q_out = (const float*)d_in[2];
    const float* w_ss  = (const float*)d_in[3];
    const float* w_vs  = (const float*)d_in[4];
    const float* w_sv  = (const float*)d_in[5];
    const float* w_vv0 = (const float*)d_in[6];
    const float* w_vv1 = (const float*)d_in[7];
    const float* bias  = (const float*)d_in[8];
    float* out = (float*)d_out;

    char* ws = (char*)d_ws;
    __hip_bfloat16* phi = (__hip_bfloat16*)(ws + 0);          //  2,097,152 B
    __hip_bfloat16* xtp = (__hip_bfloat16*)(ws + 2097152);    //  1,105,920 B
    __hip_bfloat16* w2  = (__hip_bfloat16*)(ws + 3203072);    //     40,960 B
    char*           E2  = (char*)(ws + 3244032);              // 20,971,520 B (total 24.2 MB)

    const int PREP_N = PHI_N + VOX_N + W2_N;                  // 1,103,616 = 4311*256
    hipLaunchKernelGGL(prep_kernel, dim3(PREP_N / 256), dim3(256), 0, stream,
                       x, q_in, q_out, w_ss, w_vs, w_sv, w_vv0, w_vv1,
                       phi, xtp, w2);
    hipLaunchKernelGGL(gemm1_kernel, dim3(1280), dim3(128), 0, stream,
                       (const char*)phi, (const char*)xtp, E2);
    hipLaunchKernelGGL(gemm2_kernel, dim3(256), dim3(512), 0, stream,
                       (const char*)w2, (const char*)E2, bias, out);
}

// Round 12
// 111.087 us; speedup vs baseline: 1.0648x; 1.0648x over previous
//
#include <hip/hip_runtime.h>
#include <hip/hip_bf16.h>
#include <math.h>

#define C0 8
#define C1 4
#define NCH 20          // C0 + 3*C1
#define NQ 16
#define K3 125
#define G 8
#define RMAX 5.5f
#define EPSL 1e-6f

#define KD1 2048        // gemm1 K = 128 taps * 16 q
#define PHI_N 1048576   // 512 * 2048
#define XTP_N 552960    // 20*1728*16
#define W2_N 20480      // 32*20*32
#define E2C_B 10485760  // bytes per kc chunk of E2: 16*20*512*32*2

#define LDS_A 16384     // one A buffer: 128 rows * 128 B (XOR-swizzled, DMA-written)
#define LDS_B 18432     // 4 az-planes x 12x12x16 bf16 (per-kc slab) at offset 2*LDS_A
#define LDS_SZ 51200    // 2*16384 + 18432 (>= epilogue 4*8704 = 34816) -> 3 blocks/CU

using f32x4 = __attribute__((ext_vector_type(4))) float;
using s16x8 = __attribute__((ext_vector_type(8))) short;

typedef const __attribute__((address_space(1))) unsigned int gq_t;
typedef __attribute__((address_space(3))) unsigned int lq_t;

__device__ __forceinline__ float epsf(int i, int m, int j) {
    if (i == m || m == j || i == j) return 0.f;
    return (m == (i + 1) % 3) ? 1.f : -1.f;
}

// ---------------- prep: phi, xtp, w2 (bf16) ----------------
// phi[m=p*32+b][t*16+q]  b = g*4+mi, mi: 0=R, 1..3 = R*u_{z,y,x}; t>=125 zero
// xtp[c][az][ay][ax][q]  zero-padded 12^3
// w2 [o=32pad][c=20][b=32]
__global__ __launch_bounds__(256) void prep_kernel(
    const float* __restrict__ x,
    const float* __restrict__ q_in, const float* __restrict__ q_out,
    const float* __restrict__ w_ss, const float* __restrict__ w_vs,
    const float* __restrict__ w_sv, const float* __restrict__ w_vv0,
    const float* __restrict__ w_vv1,
    __hip_bfloat16* __restrict__ phi, __hip_bfloat16* __restrict__ xtp,
    __hip_bfloat16* __restrict__ w2)
{
    int gid = blockIdx.x * 256 + threadIdx.x;   // exact grid
    if (gid < PHI_N) {
        int col = gid & (KD1 - 1); int m = gid >> 11;
        int t = col >> 4, q = col & 15;
        int p = m >> 5,  b = m & 31;
        int g = b >> 2,  mi = b & 3;
        float val = 0.f;
        if (t < K3) {
            int tz = t / 25, ty = (t / 5) % 5, tx = t % 5;
            float vz = (float)(tz - 2) - (q_out[p*3+0] - q_in[q*3+0]);
            float vy = (float)(ty - 2) - (q_out[p*3+1] - q_in[q*3+1]);
            float vx = (float)(tx - 2) - (q_out[p*3+2] - q_in[q*3+2]);
            float r  = sqrtf(vz*vz + vy*vy + vx*vx);
            float inv = (r > EPSL) ? (1.0f / r) : 0.0f;
            const float sigma = RMAX / (float)(G - 1);
            float d = (r - (RMAX * (float)g / (float)(G - 1))) / sigma;
            float Rg = expf(-0.5f * d * d);
            float u = (mi == 1) ? vz*inv : ((mi == 2) ? vy*inv : vx*inv);
            val = (mi == 0) ? Rg : Rg * u;
        }
        phi[gid] = __float2bfloat16(val);
    } else if (gid < PHI_N + XTP_N) {
        int g2 = gid - PHI_N;
        int q = g2 & 15; int r = g2 >> 4;
        int ax = r % 12; r /= 12;
        int ay = r % 12; r /= 12;
        int az = r % 12; int c = r / 12;
        int iz = az - 2, iy = ay - 2, ix = ax - 2;
        bool valid = ((unsigned)iz < 8u) & ((unsigned)iy < 8u) & ((unsigned)ix < 8u);
        float v = valid ? x[((c * NQ + q) << 9) + (iz << 6) + (iy << 3) + ix] : 0.f;
        xtp[g2] = __float2bfloat16(v);
    } else {
        int id = gid - (PHI_N + XTP_N);
        int b = id & 31; int r = id >> 5;
        int c = r % NCH; int o = r / NCH;
        int g = b >> 2,  mi = b & 3;
        float val = 0.f;
        if (o < NCH) {
            if (o < C0) {
                if (c < C0) { if (mi == 0) val = w_ss[(o * C0 + c) * G + g]; }
                else { int cv = (c - C0) / 3, j = (c - C0) % 3;
                       if (mi == 1 + j) val = w_sv[(o * C1 + cv) * G + g]; }
            } else {
                int ov = (o - C0) / 3, i = (o - C0) % 3;
                if (c < C0) { if (mi == 1 + i) val = w_vs[(ov * C0 + c) * G + g]; }
                else {
                    int cv = (c - C0) / 3, j = (c - C0) % 3;
                    if (mi == 0) { if (i == j) val = w_vv0[(ov * C1 + cv) * G + g]; }
                    else val = 0.7071067811865476f * w_vv1[(ov * C1 + cv) * G + g]
                               * epsf(i, mi - 1, j);
                }
            }
        }
        w2[id] = __float2bfloat16(val);
    }
}

// ---------------- gemm1: dbuf A-DMA + counted vmcnt at 3 blocks/CU (4-plane B slab) ----------------
// grid 640 = kc(2) x pg(4: 128 m-rows = 4 p's) x c(20) x zq(4: 128 z)
// block 256 thr = 2x2 waves of 64x64; 16 chunks of 64 k-elems (4 taps)
// Per j: [lgkm0;bar] -> issue DMA(j+1) -> [vmcnt(4);bar] -> compute(j).
// kc chunk touches only 4 az planes (kc=0: tz 0-2; kc=1: tz 2-4) -> 18432 B slab.
__global__ __launch_bounds__(256, 3) void gemm1_kernel(
    const char* __restrict__ phi_b, const char* __restrict__ xtp_b,
    char* __restrict__ E2_b)
{
    __shared__ __align__(16) char lds[LDS_SZ];

    int tid = threadIdx.x;
    int wave = tid >> 6, lane = tid & 63;
    int row = lane & 15, quad = lane >> 4;
    int wi = wave >> 1, wj = wave & 1;
    int hi = quad >> 1;

    int bi = blockIdx.x;                 // 640
    int kc = bi / 320;
    int r  = bi - kc * 320;
    int pg = r / 80;
    int r2 = r - pg * 80;
    int c  = r2 >> 2;
    int zq = r2 & 3;

    // ---- B slab: xtp[c][az = 2zq+2kc .. +3][ay][ax][q], 18432 B, XOR-swizzled ----
    {
        const char* src = xtp_b + c * 55296 + (zq + kc) * 9216;
        for (int i = tid; i < 1152; i += 256) {
            int d = (i * 16) ^ (((i >> 1) & 7) << 4);
            *(s16x8*)(lds + 2 * LDS_A + d) = *(const s16x8*)(src + i * 16);
        }
    }

    // ---- A DMA source pointers: wave chunk i covers LDS [(wave*4+i)*1024, +1024).
    // lane dest d = chunk*1024 + lane*16; source elem = d ^ ((d>>7&7)<<4)
    // -> row = pg*128 + wave*32 + i*8 + (lane>>3), col-slot = (lane&7)^((lane>>3)&7).
    const char* gA[4];
    {
        int lrow = lane >> 3;
        int cslot = (lane & 7) ^ (lrow & 7);
        #pragma unroll
        for (int i = 0; i < 4; ++i)
            gA[i] = phi_b + (size_t)(pg * 128 + wave * 32 + i * 8 + lrow) * 4096
                    + kc * 2048 + cslot * 16;
    }
    int arx = (row & 7) << 4;            // af read-side XOR key

    // per-lane B LDS pre-offsets (linear; swizzle applied at read; base 2*LDS_A has bits 4-6 clear)
    int bpre[4];
    #pragma unroll
    for (int nt = 0; nt < 4; ++nt) {
        int zl = wj * 64 + nt * 16 + row;
        int zz = zl >> 6, zy = (zl >> 3) & 7, zx = zl & 7;
        bpre[nt] = (zz * 144 + zy * 12 + zx) * 32 + (quad & 1) * 16;
    }

    f32x4 acc[4][4];
    #pragma unroll
    for (int i = 0; i < 4; ++i)
        #pragma unroll
        for (int j = 0; j < 4; ++j) acc[i][j] = (f32x4){0.f, 0.f, 0.f, 0.f};

    // ---- prologue: DMA A(0) into buf0; drain everything; barrier (B + A0 visible) ----
    #pragma unroll
    for (int i = 0; i < 4; ++i)
        __builtin_amdgcn_global_load_lds(
            (gq_t*)(gA[i]), (lq_t*)(lds + (wave * 4 + i) * 1024), 16, 0, 0);
    asm volatile("s_waitcnt vmcnt(0) lgkmcnt(0)" ::: "memory");
    __builtin_amdgcn_sched_barrier(0);
    __builtin_amdgcn_s_barrier();
    __builtin_amdgcn_sched_barrier(0);

    int cur = 0;
    for (int j = 0; j < 16; ++j) {
        // (A) overwrite-safety: all waves' LDS reads of buf[cur^1] (compute j-1) retired
        asm volatile("s_waitcnt lgkmcnt(0)" ::: "memory");
        __builtin_amdgcn_sched_barrier(0);
        __builtin_amdgcn_s_barrier();
        __builtin_amdgcn_sched_barrier(0);
        if (j < 15) {
            #pragma unroll
            for (int i = 0; i < 4; ++i)
                __builtin_amdgcn_global_load_lds(
                    (gq_t*)(gA[i] + (j + 1) * 128),
                    (lq_t*)(lds + (cur ^ 1) * LDS_A + (wave * 4 + i) * 1024), 16, 0, 0);
            asm volatile("s_waitcnt vmcnt(4)" ::: "memory");   // DMA(j) done; DMA(j+1) in flight
        } else {
            asm volatile("s_waitcnt vmcnt(0)" ::: "memory");   // drain last chunk
        }
        __builtin_amdgcn_sched_barrier(0);
        __builtin_amdgcn_s_barrier();      // (B) A(j) visible from all waves
        __builtin_amdgcn_sched_barrier(0);

        int toff[4];
        #pragma unroll
        for (int tt = 0; tt < 4; ++tt) {
            int t = kc * 64 + j * 4 + tt; if (t > 124) t = 124;  // pad taps: phi=0
            int tz = t / 25, trm = t - tz * 25;
            int ty = trm / 5, tx = trm - ty * 5;
            toff[tt] = ((tz - 2 * kc) * 144 + ty * 12 + tx) * 32;  // per-kc plane base
        }
        #pragma unroll
        for (int st = 0; st < 2; ++st) {
            s16x8 af[4], bf[4];
            #pragma unroll
            for (int mt = 0; mt < 4; ++mt) {
                int aa = ((wi * 64 + mt * 16 + row) * 128 + (st * 4 + quad) * 16) ^ arx;
                af[mt] = *(const s16x8*)(lds + cur * LDS_A + aa);
            }
            int tsel = toff[st * 2 + hi];
            #pragma unroll
            for (int nt = 0; nt < 4; ++nt) {
                int ba = bpre[nt] + tsel;
                ba ^= ((ba >> 5) & 7) << 4;
                bf[nt] = *(const s16x8*)(lds + 2 * LDS_A + ba);
            }
            #pragma unroll
            for (int mt = 0; mt < 4; ++mt)
                #pragma unroll
                for (int nt = 0; nt < 4; ++nt)
                    acc[mt][nt] = __builtin_amdgcn_mfma_f32_16x16x32_bf16(
                        af[mt], bf[nt], acc[mt][nt], 0, 0, 0);
        }
        cur ^= 1;
    }
    __syncthreads();                     // all compute done; LDS reusable

    // ---- epilogue: wave-private LDS transpose -> 1KB-contiguous stores ----
    int wbase = wave * 8704;                     // 64 zl x 136 B
    #pragma unroll
    for (int mt = 0; mt < 4; ++mt) {
        #pragma unroll
        for (int nt = 0; nt < 4; ++nt) {
            int zl = nt * 16 + row;
            union { unsigned long long u; __hip_bfloat16 h[4]; } pk;
            pk.h[0] = __float2bfloat16(acc[mt][nt][0]);
            pk.h[1] = __float2bfloat16(acc[mt][nt][1]);
            pk.h[2] = __float2bfloat16(acc[mt][nt][2]);
            pk.h[3] = __float2bfloat16(acc[mt][nt][3]);
            *(unsigned long long*)(lds + wbase + zl * 136 + (mt * 16 + quad * 4) * 2) = pk.u;
        }
    }
    // wave-local exchange: no barrier needed
    char* Ek = E2_b + (size_t)kc * E2C_B;
    int pbase = pg * 4 + wi * 2;
    #pragma unroll
    for (int it = 0; it < 8; ++it) {
        int item = lane + it * 64;
        int piece = item & 3;
        int zl = (item >> 2) & 63;
        int h  = item >> 8;
        s16x8 v = *(const s16x8*)(lds + wbase + zl * 136 + h * 64 + piece * 16);
        int p = pbase + h;
        int z = zq * 128 + wj * 64 + zl;
        *(s16x8*)(Ek + ((size_t)((p * NCH + c) << 9) + z) * 64 + piece * 16) = v;
    }
}

// ---------------- gemm2: 4-way K-split + LDS reduce, direct store (no atomics) ----------------
// grid 256 = p(16) x zb(16: 32 z); block 512 thr = 8 waves = zh(2: 16-z half) x ks(4: K=320)
__global__ __launch_bounds__(512) void gemm2_kernel(
    const char* __restrict__ w2_b, const char* __restrict__ E2_b,
    const float* __restrict__ bias, float* __restrict__ out)
{
    __shared__ float red[3][2][64][8];   // [ks-1][zh][lane][mt*4+ri]

    int tid = threadIdx.x;
    int wave = tid >> 6, lane = tid & 63;
    int row = lane & 15, quad = lane >> 4;
    int zh = wave & 1, ks = wave >> 1;
    int bi = blockIdx.x;                 // 256
    int p  = bi >> 4;
    int zb = bi & 15;
    int z  = zb * 32 + zh * 16 + row;

    int kcq = ks >> 1;                   // kc chunk
    int cb  = (ks & 1) * 10;             // cc base within chunk
    const char* bbase = E2_b + (size_t)kcq * E2C_B + (size_t)p * 655360
                        + (size_t)z * 64 + quad * 16;

    f32x4 acc[2];
    acc[0] = (f32x4){0.f, 0.f, 0.f, 0.f};
    acc[1] = (f32x4){0.f, 0.f, 0.f, 0.f};

    #pragma unroll
    for (int ci = 0; ci < 10; ++ci) {
        int cc = cb + ci;
        s16x8 a0 = *(const s16x8*)(w2_b + (row)      * 1280 + cc * 64 + quad * 16);
        s16x8 a1 = *(const s16x8*)(w2_b + (16 + row) * 1280 + cc * 64 + quad * 16);
        s16x8 b  = *(const s16x8*)(bbase + (size_t)cc * 32768);
        acc[0] = __builtin_amdgcn_mfma_f32_16x16x32_bf16(a0, b, acc[0], 0, 0, 0);
        acc[1] = __builtin_amdgcn_mfma_f32_16x16x32_bf16(a1, b, acc[1], 0, 0, 0);
    }

    if (ks != 0) {
        #pragma unroll
        for (int mt = 0; mt < 2; ++mt)
            #pragma unroll
            for (int ri = 0; ri < 4; ++ri)
                red[ks - 1][zh][lane][mt * 4 + ri] = acc[mt][ri];
    }
    __syncthreads();
    if (ks == 0) {
        #pragma unroll
        for (int s = 0; s < 3; ++s)
            #pragma unroll
            for (int mt = 0; mt < 2; ++mt)
                #pragma unroll
                for (int ri = 0; ri < 4; ++ri)
                    acc[mt][ri] += red[s][zh][lane][mt * 4 + ri];
        #pragma unroll
        for (int mt = 0; mt < 2; ++mt)
            #pragma unroll
            for (int ri = 0; ri < 4; ++ri) {
                int o = mt * 16 + quad * 4 + ri;
                if (o < NCH) {
                    float v = acc[mt][ri];
                    if (o < C0) v += bias[o];
                    out[((o * NQ + p) << 9) + z] = v;
                }
            }
    }
}

extern "C" void kernel_launch(void* const* d_in, const int* in_sizes, int n_in,
                              void* d_out, int out_size, void* d_ws, size_t ws_size,
                              hipStream_t stream) {
    const float* x     = (const float*)d_in[0];
    const float* q_in  = (const float*)d_in[1];
    const float* q_out = (const float*)d_in[2];
    const float* w_ss  = (const float*)d_in[3];
    const float* w_vs  = (const float*)d_in[4];
    const float* w_sv  = (const float*)d_in[5];
    const float* w_vv0 = (const float*)d_in[6];
    const float* w_vv1 = (const float*)d_in[7];
    const float* bias  = (const float*)d_in[8];
    float* out = (float*)d_out;

    char* ws = (char*)d_ws;
    __hip_bfloat16* phi = (__hip_bfloat16*)(ws + 0);          //  2,097,152 B
    __hip_bfloat16* xtp = (__hip_bfloat16*)(ws + 2097152);    //  1,105,920 B
    __hip_bfloat16* w2  = (__hip_bfloat16*)(ws + 3203072);    //     40,960 B
    char*           E2  = (char*)(ws + 3244032);              // 20,971,520 B (total 24.2 MB)

    const int PREP_N = PHI_N + XTP_N + W2_N;                  // 1,622,016 = 6336*256
    hipLaunchKernelGGL(prep_kernel, dim3(PREP_N / 256), dim3(256), 0, stream,
                       x, q_in, q_out, w_ss, w_vs, w_sv, w_vv0, w_vv1,
                       phi, xtp, w2);
    hipLaunchKernelGGL(gemm1_kernel, dim3(640), dim3(256), 0, stream,
                       (const char*)phi, (const char*)xtp, E2);
    hipLaunchKernelGGL(gemm2_kernel, dim3(256), dim3(512), 0, stream,
                       (const char*)w2, (const char*)E2, bias, out);
}